// Round 7
// baseline (1100.864 us; speedup 1.0000x reference)
//
#include <hip/hip_runtime.h>

#define NSAMP 2048
#define NCONF 128
#define NMO   64
#define NE    16   // electrons per spin (matrix dim)

// Block = 256 threads = 2 samples x 128 configs.
// LDS: samples staged TRANSPOSED (column-major per (sample,spin) plane) with
// XOR swizzle on the 16B slot: word(c,r)=c*16+(((r>>2)^h(c))<<2)|(r&3),
// h(c)=(c^(c>>2))&3. One matrix column = 4 x ds_read_b128.
//
// Per thread: det(up)*det(dn) via LEFT-LOOKING Householder QR; scaled
// reflectors V (136 floats) in registers. Manual 1-deep pipeline: column j+1
// is loaded into buf[(j+1)&1] while column j computes; sched_barrier(0) at
// each iteration end stops the unrolled scheduler from hoisting deeper
// (bounds live ranges so (256,2) fits 256 arch VGPRs, no AGPR round-trips --
// round 6 at (256,1) parked V in AGPRs: VGPR_Count=112, occ 16%, +35% VALU).
__global__ __launch_bounds__(256, 2)
void SlaterPooling_45543833207162_kernel(const float* __restrict__ x,
                                         const int*   __restrict__ cup,
                                         const int*   __restrict__ cdn,
                                         float*       __restrict__ out) {
  __shared__ float tile[4 * 64 * NE];   // 4 planes x 64 cols x 16 rows = 16 KB
  float4* tile4 = reinterpret_cast<float4*>(tile);

  // ---- stage 16 KB coalesced; write transposed + swizzled ----
  {
    const float4* src = reinterpret_cast<const float4*>(
        x + (size_t)blockIdx.x * 2 * (2 * NE * NMO));
#pragma unroll
    for (int k = 0; k < 4; ++k) {
      const int   f4 = threadIdx.x + k * 256;   // float4 index in block region
      const float4 v = src[f4];
      const int flat  = f4 * 4;                 // word index (row-major global)
      const int plane = flat >> 10;             // (s_local, spin) plane 0..3
      const int r     = (flat >> 6) & 15;       // row within plane
      const int c4    = (flat >> 2) & 15;       // c = 4*c4 + d
      const int rlo = r & 3, rhi = r >> 2;
      const float vv[4] = {v.x, v.y, v.z, v.w};
#pragma unroll
      for (int d = 0; d < 4; ++d) {
        const int c = 4 * c4 + d;
        const int h = (d ^ c4) & 3;             // == (c ^ (c>>2)) & 3
        tile[plane * 1024 + c * NE + (((rhi ^ h) << 2) | rlo)] = vv[d];
      }
    }
  }
  __syncthreads();

  const int s_local = threadIdx.x >> 7;         // 0..1
  const int c       = threadIdx.x & 127;        // config index
  float result = 1.0f;

  // spin loop NOT unrolled: V and buffers reused across spins
#pragma unroll 1
  for (int spin = 0; spin < 2; ++spin) {
    const int4* cfg4 = reinterpret_cast<const int4*>(
        (spin ? cdn : cup) + c * NE);
    const float4* plane4 = tile4 + (s_local * 2 + spin) * 256;

    float V[NE - 1][NE];   // scaled reflector k in V[k][k..15]
    float det = -1.0f;     // (-1)^15 from 15 reflectors
    float buf[2][16];      // column double-buffer (all indices compile-time)

    int4 cw = cfg4[0];     // current group of 4 config indices
    int4 cn = cfg4[1];     // next group

    // preload column 0
    {
      const int cj = cw.x;
      const int h  = (cj ^ (cj >> 2)) & 3;
      const float4* col = plane4 + cj * 4;
      *reinterpret_cast<float4*>(&buf[0][ 0]) = col[0 ^ h];
      *reinterpret_cast<float4*>(&buf[0][ 4]) = col[1 ^ h];
      *reinterpret_cast<float4*>(&buf[0][ 8]) = col[2 ^ h];
      *reinterpret_cast<float4*>(&buf[0][12]) = col[3 ^ h];
    }

#pragma unroll
    for (int j = 0; j < NE; ++j) {
      auto& a = buf[j & 1];
      auto& b = buf[(j + 1) & 1];

      // ---- rotate config groups (compile-time after unroll) ----
      if ((j & 3) == 0 && j > 0) {
        cw = cn;
        if (j + 4 < NE) cn = cfg4[(j >> 2) + 1];
      }

      // ---- issue prefetch of column j+1 into b ----
      if (j + 1 < NE) {
        const int  e    = (j + 1) & 3;
        const bool same = (((j + 1) >> 2) == (j >> 2));
        const int4 srcw = same ? cw : cn;
        const int  cj1  = (e == 0) ? srcw.x : (e == 1) ? srcw.y
                        : (e == 2) ? srcw.z : srcw.w;
        const int  h1   = (cj1 ^ (cj1 >> 2)) & 3;
        const float4* col1 = plane4 + cj1 * 4;
        *reinterpret_cast<float4*>(&b[ 0]) = col1[0 ^ h1];
        *reinterpret_cast<float4*>(&b[ 4]) = col1[1 ^ h1];
        *reinterpret_cast<float4*>(&b[ 8]) = col1[2 ^ h1];
        *reinterpret_cast<float4*>(&b[12]) = col1[3 ^ h1];
      }

      // ---- apply reflectors 0..j-1 (k<j folds at compile time) ----
#pragma unroll
      for (int k = 0; k < NE - 1; ++k) {
        if (k < j) {
          float w4[4] = {0.f, 0.f, 0.f, 0.f};
#pragma unroll
          for (int i = k; i < NE; ++i)
            w4[i & 3] = fmaf(V[k][i], a[i], w4[i & 3]);
          const float w = (w4[0] + w4[1]) + (w4[2] + w4[3]);
#pragma unroll
          for (int i = k; i < NE; ++i)
            a[i] = fmaf(-w, V[k][i], a[i]);
        }
      }

      // ---- form reflector j (or finish det on last column) ----
      if (j < NE - 1) {
        float s4[4] = {0.f, 0.f, 0.f, 0.f};
#pragma unroll
        for (int i = j; i < NE; ++i)
          s4[i & 3] = fmaf(a[i], a[i], s4[i & 3]);
        const float s2    = (s4[0] + s4[1]) + (s4[2] + s4[3]);
        const float nrm   = __builtin_amdgcn_sqrtf(s2);
        const float ajj   = a[j];
        const float alpha = (ajj >= 0.0f) ? -nrm : nrm;     // R_jj
        const float vk    = ajj - alpha;                    // no cancellation
        const float vtv   = 2.0f * fmaf(-alpha, ajj, s2);   // v^T v
        // pre-scale v by sqrt(2/v'v): H = I - v v^T, no tau needed later
        const float scale = 1.41421356237f * __builtin_amdgcn_rsqf(vtv);
        det *= alpha;
        V[j][j] = vk * scale;
#pragma unroll
        for (int i = j + 1; i < NE; ++i) V[j][i] = a[i] * scale;
      } else {
        det *= a[NE - 1];   // R[15][15]
      }

      // fence: no scheduling across iterations beyond the explicit prefetch
      __builtin_amdgcn_sched_barrier(0);
    }
    result *= det;
  }

  // out[s*128 + c]
  out[(blockIdx.x * 2 + s_local) * NCONF + c] = result;
}

extern "C" void kernel_launch(void* const* d_in, const int* in_sizes, int n_in,
                              void* d_out, int out_size, void* d_ws, size_t ws_size,
                              hipStream_t stream) {
  const float* x   = (const float*)d_in[0];
  const int*   cup = (const int*)d_in[1];
  const int*   cdn = (const int*)d_in[2];
  float*       out = (float*)d_out;

  dim3 grid(NSAMP / 2), block(256);   // 1024 blocks, 2 samples each
  hipLaunchKernelGGL(SlaterPooling_45543833207162_kernel, grid, block, 0, stream,
                     x, cup, cdn, out);
}

// Round 8
// 309.690 us; speedup vs baseline: 3.5547x; 3.5547x over previous
//
#include <hip/hip_runtime.h>

#define NSAMP 2048
#define NCONF 128
#define NMO   64
#define NE    16   // electrons per spin (matrix dim)

// Block = 256 threads = 2 samples x 128 configs.
// LDS: samples staged TRANSPOSED (column-major per (sample,spin) plane) with
// XOR swizzle on the 16B slot: word(c,r)=c*16+(((r>>2)^h(c))<<2)|(r&3),
// h(c)=(c^(c>>2))&3. One matrix column = 4 x ds_read_b128.
//
// Per thread: det(up)*det(dn) via LEFT-LOOKING Householder QR processed in
// 2-COLUMN PANELS: columns 2t,2t+1 are loaded together and every reflector
// k<2t is applied to both sharing one V[k][i] read (V is AGPR-parked at
// (256,1); sharing halves the accvgpr read traffic, and the two independent
// dot chains double ILP). (256,1) is mandatory: (256,2) spilled to scratch
// in rounds 2, 4 and 7.
__global__ __launch_bounds__(256, 1)
void SlaterPooling_45543833207162_kernel(const float* __restrict__ x,
                                         const int*   __restrict__ cup,
                                         const int*   __restrict__ cdn,
                                         float*       __restrict__ out) {
  __shared__ float tile[4 * 64 * NE];   // 4 planes x 64 cols x 16 rows = 16 KB
  float4* tile4 = reinterpret_cast<float4*>(tile);

  // ---- stage 16 KB coalesced; write transposed + swizzled ----
  {
    const float4* src = reinterpret_cast<const float4*>(
        x + (size_t)blockIdx.x * 2 * (2 * NE * NMO));
#pragma unroll
    for (int k = 0; k < 4; ++k) {
      const int   f4 = threadIdx.x + k * 256;   // float4 index in block region
      const float4 v = src[f4];
      const int flat  = f4 * 4;                 // word index (row-major global)
      const int plane = flat >> 10;             // (s_local, spin) plane 0..3
      const int r     = (flat >> 6) & 15;       // row within plane
      const int c4    = (flat >> 2) & 15;       // c = 4*c4 + d
      const int rlo = r & 3, rhi = r >> 2;
      const float vv[4] = {v.x, v.y, v.z, v.w};
#pragma unroll
      for (int d = 0; d < 4; ++d) {
        const int c = 4 * c4 + d;
        const int h = (d ^ c4) & 3;             // == (c ^ (c>>2)) & 3
        tile[plane * 1024 + c * NE + (((rhi ^ h) << 2) | rlo)] = vv[d];
      }
    }
  }
  __syncthreads();

  const int s_local = threadIdx.x >> 7;         // 0..1
  const int c       = threadIdx.x & 127;        // config index
  float result = 1.0f;

  // spin loop NOT unrolled: V and panel regs reused across spins
#pragma unroll 1
  for (int spin = 0; spin < 2; ++spin) {
    const int4* cfg4 = reinterpret_cast<const int4*>(
        (spin ? cdn : cup) + c * NE);
    const int4 q0 = cfg4[0], q1 = cfg4[1], q2 = cfg4[2], q3 = cfg4[3];
    const int cidx[16] = {q0.x, q0.y, q0.z, q0.w,  q1.x, q1.y, q1.z, q1.w,
                          q2.x, q2.y, q2.z, q2.w,  q3.x, q3.y, q3.z, q3.w};

    const float4* plane4 = tile4 + (s_local * 2 + spin) * 256;

    float V[NE - 1][NE];   // scaled reflector k in V[k][k..15]
    float det = -1.0f;     // (-1)^15 from 15 reflectors

#pragma unroll
    for (int t = 0; t < NE / 2; ++t) {
      const int j0 = 2 * t, j1 = 2 * t + 1;

      // ---- load panel columns j0, j1 (4 x ds_read_b128 each) ----
      float a0[NE], a1[NE];
      {
        const int cj = cidx[j0];
        const int h  = (cj ^ (cj >> 2)) & 3;
        const float4* col = plane4 + cj * 4;
        { const float4 v = col[0 ^ h]; a0[ 0]=v.x; a0[ 1]=v.y; a0[ 2]=v.z; a0[ 3]=v.w; }
        { const float4 v = col[1 ^ h]; a0[ 4]=v.x; a0[ 5]=v.y; a0[ 6]=v.z; a0[ 7]=v.w; }
        { const float4 v = col[2 ^ h]; a0[ 8]=v.x; a0[ 9]=v.y; a0[10]=v.z; a0[11]=v.w; }
        { const float4 v = col[3 ^ h]; a0[12]=v.x; a0[13]=v.y; a0[14]=v.z; a0[15]=v.w; }
      }
      {
        const int cj = cidx[j1];
        const int h  = (cj ^ (cj >> 2)) & 3;
        const float4* col = plane4 + cj * 4;
        { const float4 v = col[0 ^ h]; a1[ 0]=v.x; a1[ 1]=v.y; a1[ 2]=v.z; a1[ 3]=v.w; }
        { const float4 v = col[1 ^ h]; a1[ 4]=v.x; a1[ 5]=v.y; a1[ 6]=v.z; a1[ 7]=v.w; }
        { const float4 v = col[2 ^ h]; a1[ 8]=v.x; a1[ 9]=v.y; a1[10]=v.z; a1[11]=v.w; }
        { const float4 v = col[3 ^ h]; a1[12]=v.x; a1[13]=v.y; a1[14]=v.z; a1[15]=v.w; }
      }

      // ---- apply reflectors 0..j0-1 to BOTH columns (shared V reads) ----
#pragma unroll
      for (int k = 0; k < NE - 1; ++k) {
        if (k < j0) {
          float w0a = 0.f, w0b = 0.f, w1a = 0.f, w1b = 0.f;
#pragma unroll
          for (int i = k; i < NE; ++i) {
            const float vki = V[k][i];
            if (i & 1) { w0b = fmaf(vki, a0[i], w0b); w1b = fmaf(vki, a1[i], w1b); }
            else       { w0a = fmaf(vki, a0[i], w0a); w1a = fmaf(vki, a1[i], w1a); }
          }
          const float w0 = w0a + w0b, w1 = w1a + w1b;
          // element i=k is never read again -> start update at k+1
#pragma unroll
          for (int i = k + 1; i < NE; ++i) {
            const float vki = V[k][i];
            a0[i] = fmaf(-w0, vki, a0[i]);
            a1[i] = fmaf(-w1, vki, a1[i]);
          }
        }
      }

      // ---- form reflector j0 from a0 ----
      {
        float sa = 0.f, sb = 0.f, sc = 0.f, sd = 0.f;
#pragma unroll
        for (int i = j0; i < NE; ++i) {
          const int m = i & 3;
          if      (m == 0) sa = fmaf(a0[i], a0[i], sa);
          else if (m == 1) sb = fmaf(a0[i], a0[i], sb);
          else if (m == 2) sc = fmaf(a0[i], a0[i], sc);
          else             sd = fmaf(a0[i], a0[i], sd);
        }
        const float s2    = (sa + sb) + (sc + sd);
        const float nrm   = __builtin_amdgcn_sqrtf(s2);
        const float ajj   = a0[j0];
        const float alpha = (ajj >= 0.0f) ? -nrm : nrm;     // R_{j0,j0}
        const float vk    = ajj - alpha;                    // no cancellation
        const float vtv   = 2.0f * fmaf(-alpha, ajj, s2);   // v^T v
        const float scale = 1.41421356237f * __builtin_amdgcn_rsqf(vtv);
        det *= alpha;
        V[j0][j0] = vk * scale;
#pragma unroll
        for (int i = j0 + 1; i < NE; ++i) V[j0][i] = a0[i] * scale;
      }

      // ---- apply reflector j0 to a1 (dot i>=j0, update i>=j1) ----
      {
        float wa = 0.f, wb = 0.f;
#pragma unroll
        for (int i = j0; i < NE; ++i) {
          if (i & 1) wb = fmaf(V[j0][i], a1[i], wb);
          else       wa = fmaf(V[j0][i], a1[i], wa);
        }
        const float w = wa + wb;
#pragma unroll
        for (int i = j1; i < NE; ++i)
          a1[i] = fmaf(-w, V[j0][i], a1[i]);
      }

      // ---- form reflector j1 (or finish det on the last column) ----
      if (j1 < NE - 1) {
        float sa = 0.f, sb = 0.f, sc = 0.f, sd = 0.f;
#pragma unroll
        for (int i = j1; i < NE; ++i) {
          const int m = i & 3;
          if      (m == 0) sa = fmaf(a1[i], a1[i], sa);
          else if (m == 1) sb = fmaf(a1[i], a1[i], sb);
          else if (m == 2) sc = fmaf(a1[i], a1[i], sc);
          else             sd = fmaf(a1[i], a1[i], sd);
        }
        const float s2    = (sa + sb) + (sc + sd);
        const float nrm   = __builtin_amdgcn_sqrtf(s2);
        const float ajj   = a1[j1];
        const float alpha = (ajj >= 0.0f) ? -nrm : nrm;     // R_{j1,j1}
        const float vk    = ajj - alpha;
        const float vtv   = 2.0f * fmaf(-alpha, ajj, s2);
        const float scale = 1.41421356237f * __builtin_amdgcn_rsqf(vtv);
        det *= alpha;
        V[j1][j1] = vk * scale;
#pragma unroll
        for (int i = j1 + 1; i < NE; ++i) V[j1][i] = a1[i] * scale;
      } else {
        det *= a1[NE - 1];   // R[15][15]
      }
    }
    result *= det;
  }

  // out[s*128 + c]
  out[(blockIdx.x * 2 + s_local) * NCONF + c] = result;
}

extern "C" void kernel_launch(void* const* d_in, const int* in_sizes, int n_in,
                              void* d_out, int out_size, void* d_ws, size_t ws_size,
                              hipStream_t stream) {
  const float* x   = (const float*)d_in[0];
  const int*   cup = (const int*)d_in[1];
  const int*   cdn = (const int*)d_in[2];
  float*       out = (float*)d_out;

  dim3 grid(NSAMP / 2), block(256);   // 1024 blocks, 2 samples each
  hipLaunchKernelGGL(SlaterPooling_45543833207162_kernel, grid, block, 0, stream,
                     x, cup, cdn, out);
}